// Round 23
// baseline (525.779 us; speedup 1.0000x reference)
//
#include <hip/hip_runtime.h>

// Capsule routing, B=64 R=2048 C=32 O=32 I=16, 3 routing iters.
// u_hat never materialized; recomputed per pass. Logit telescoping:
// b1 = u.v1 ; b2 = u.(v1+v2).
//
// R34 = R32 resubmit x2 (R32 GPUAcquisitionTimeout; R33 container failed
//   twice — bounds re-audited: Wh paired store/read max index ends exactly
//   at the 64MB boundary, no OOB; infra flake assumed).
// R32: 16B W-LOADS in phases 1/2 via r-paired Wh layout.
//   R31 post-mortem: barrier halving NEUTRAL (+5us) => barrier theory
//   closed. Remaining anomaly: ph0 streams 4.3 TB/s with 16B/lane loads;
//   ph1/2 2.2 TB/s with 8B/lane — same instr count, same structure =>
//   latency/issue-bound regime pays per LOAD, not per byte. Fix: phase 0
//   persists Wh in r-PAIRED layout Wh2[r/2][co][q][p] so ph1/2 read one
//   b128 per (m, rr-pair) = frags for BOTH rr's (lo/hi half4). 8 x b128
//   per pair replaces 16 x b64; prefetch one pair ahead (2 barrier cycles
//   of cover). Per-rr math identical to R30 (same roundings).
//   Pre-commit: neutral => load-width theory dead; structure at floor.
// R30 (kept): fp16 s_part (16 MB); RCH=16, 256 blocks, bound=1.
// R25 (kept): wconv folded into upass<0> (fp32 W read, bg==0 persists Wh).
// R15 (kept): NG=2 b-fusion, 32 b/block; fused reduce_squash.
// R11 baseline: MFMA 16x16x16 per tile; D row=4q+reg, col=lane&15.

#define Bn 64
#define Rn 2048
#define Cn 32
#define On 32
#define In 16
#define RCH 16            // r per block
#define NRC2 (Rn / RCH)   // 128 r-chunks
#define NG 2              // fused b-groups of 32

typedef _Float16 half4v __attribute__((ext_vector_type(4)));
typedef _Float16 half8v __attribute__((ext_vector_type(8)));
typedef float floatx4 __attribute__((ext_vector_type(4)));

// s_part: [NRC2][64 b][1024 co] fp16 (16 MB)
// Wh paired layout: half index ((r>>1)*1024 + co)*32 + q*8 + (r&1)*4
template <int PHASE>
__global__ __launch_bounds__(512, 1)
void upass(const float* __restrict__ x, const float* __restrict__ Wfp,
           _Float16* __restrict__ Wh, const float* __restrict__ vroute,
           _Float16* __restrict__ s_part) {
    const int tid  = threadIdx.x;
    const int w    = tid >> 6;      // wave 0..7 -> c = 4w..4w+3
    const int lane = tid & 63;
    const int q    = lane >> 4;     // quad
    const int bl   = lane & 15;     // A row / B col / D col

    // XCD swizzle: the 2 bg-blocks of one rc are L and L+8 -> same XCD.
    const int L  = blockIdx.x;                  // [0,256)
    const int bg = (L >> 3) & 1;
    const int rc = (L & 7) | ((L >> 4) << 3);   // [0,128)
    const int b0 = bg * 32;

    // xs[rr][bb 32][20] halfs (pad 16->20: 8B-aligned b64, conflict-free)
    __shared__ __attribute__((aligned(16))) _Float16 xs[RCH * 32 * 20];
    __shared__ __attribute__((aligned(16))) float sums[2][2][16][8];

    // ---- v slice -> registers (r-invariant). g=0: b0+bl, g=1: b0+16+bl ----
    floatx4 v00[4], v01[4], v10[4], v11[4];
    if constexpr (PHASE > 0) {
        const float* vb0 = vroute + (size_t)(b0 + bl) * 1024 + 4 * q;
        const float* vb1 = vroute + (size_t)(b0 + 16 + bl) * 1024 + 4 * q;
#pragma unroll
        for (int t = 0; t < 4; ++t) {
            const int co = (w * 4 + t) * 32;
            v00[t] = *(const floatx4*)(vb0 + co);
            v01[t] = *(const floatx4*)(vb0 + co + 16);
            v10[t] = *(const floatx4*)(vb1 + co);
            v11[t] = *(const floatx4*)(vb1 + co + 16);
        }
    }

    // ---- preload x chunk -> fp16 LDS: 16 r x 32 b x 16 i ----
#pragma unroll
    for (int k = 0; k < 4; ++k) {
        const int u  = tid + k * 512;           // [0,2048)
        const int rr = u >> 7, bb = (u >> 2) & 31, iq = u & 3;
        const float4 xv = *(const float4*)(x + (size_t)(b0 + bb) * (Rn * In) +
                                           (size_t)(rc * RCH + rr) * In + iq * 4);
        union { _Float16 h[4]; uint2 u2; } p;
        p.h[0] = (_Float16)xv.x; p.h[1] = (_Float16)xv.y;
        p.h[2] = (_Float16)xv.z; p.h[3] = (_Float16)xv.w;
        *(uint2*)(xs + (rr * 32 + bb) * 20 + iq * 4) = p.u2;
    }
    __syncthreads();

    floatx4 accS0[8], accS1[8];
#pragma unroll
    for (int m = 0; m < 8; ++m) {
        accS0[m] = (floatx4){0.f, 0.f, 0.f, 0.f};
        accS1[m] = (floatx4){0.f, 0.f, 0.f, 0.f};
    }

    const int cobase = w * 128 + bl;

    if constexpr (PHASE == 0) {
        // fp32 source base: W[r][co][i] linear; per-r stride 16384 elems
        const size_t abase = ((size_t)(rc * RCH) * 1024 + cobase) * 16 + 4 * q;
        for (int rr = 0; rr < RCH; ++rr) {
            const float* Wf = Wfp + abase + (size_t)rr * 16384;
            half4v af[8];
#pragma unroll
            for (int m = 0; m < 8; ++m) {
                const float4 t4 = *(const float4*)(Wf + m * 256);
                af[m] = (half4v){(_Float16)t4.x, (_Float16)t4.y,
                                 (_Float16)t4.z, (_Float16)t4.w};
            }
            if (bg == 0) {
                // paired layout: ((r>>1)*1024 + co)*32 + q*8 + (r&1)*4
                const size_t rg = (size_t)(rc * RCH + rr);
                _Float16* whp = Wh + ((rg >> 1) * 1024 + cobase) * 32 + q * 8 + (rg & 1) * 4;
#pragma unroll
                for (int m = 0; m < 8; ++m) *(half4v*)(whp + m * 512) = af[m];
            }
            const half4v b0v = *(const half4v*)(xs + (rr * 32 + bl) * 20 + 4 * q);
            const half4v b1v = *(const half4v*)(xs + (rr * 32 + 16 + bl) * 20 + 4 * q);
#pragma unroll
            for (int m = 0; m < 8; ++m) {
                accS0[m] = __builtin_amdgcn_mfma_f32_16x16x16f16(af[m], b0v, accS0[m], 0, 0, 0);
                accS1[m] = __builtin_amdgcn_mfma_f32_16x16x16f16(af[m], b1v, accS1[m], 0, 0, 0);
            }
        }
    } else {
        // paired base for this chunk: r2 = (rc*RCH)>>1; per-m stride 512 halfs;
        // per-pair stride 32768 halfs.
        const size_t pbase = (((size_t)(rc * RCH) >> 1) * 1024 + cobase) * 32 + q * 8;
        half8v pa[8], pan[8];
#pragma unroll
        for (int m = 0; m < 8; ++m) pa[m] = *(const half8v*)(Wh + pbase + m * 512);

        for (int rr2 = 0; rr2 < RCH; rr2 += 2) {
            // prefetch next pair NOW; flies across two softmax/barrier cycles
            const int p2n = (rr2 + 2 < RCH) ? (rr2 + 2) >> 1 : rr2 >> 1;
            const _Float16* Wn = Wh + pbase + (size_t)p2n * 32768;
#pragma unroll
            for (int m = 0; m < 8; ++m) pan[m] = *(const half8v*)(Wn + m * 512);

#pragma unroll
            for (int s = 0; s < 2; ++s) {
                const int rr = rr2 + s;
                half4v a[8];
#pragma unroll
                for (int m = 0; m < 8; ++m)
                    a[m] = s ? __builtin_shufflevector(pa[m], pa[m], 4, 5, 6, 7)
                             : __builtin_shufflevector(pa[m], pa[m], 0, 1, 2, 3);
                const half4v bf0 = *(const half4v*)(xs + (rr * 32 + bl) * 20 + 4 * q);
                const half4v bf1 = *(const half4v*)(xs + (rr * 32 + 16 + bl) * 20 + 4 * q);

                floatx4 D0[8], D1[8];
#pragma unroll
                for (int m = 0; m < 8; ++m) {
                    D0[m] = __builtin_amdgcn_mfma_f32_16x16x16f16(
                                a[m], bf0, (floatx4){0.f, 0.f, 0.f, 0.f}, 0, 0, 0);
                    D1[m] = __builtin_amdgcn_mfma_f32_16x16x16f16(
                                a[m], bf1, (floatx4){0.f, 0.f, 0.f, 0.f}, 0, 0, 0);
                }

                // logits l[b,c] = sum_o u*v ; tile 2t: o=4q+reg, 2t+1: o=16+4q+reg
                float e0[4], e1[4], se0 = 0.f, se1 = 0.f;
#pragma unroll
                for (int t = 0; t < 4; ++t) {
                    float lp0 = D0[2*t].x * v00[t].x + D0[2*t].y * v00[t].y +
                                D0[2*t].z * v00[t].z + D0[2*t].w * v00[t].w +
                                D0[2*t+1].x * v01[t].x + D0[2*t+1].y * v01[t].y +
                                D0[2*t+1].z * v01[t].z + D0[2*t+1].w * v01[t].w;
                    float lp1 = D1[2*t].x * v10[t].x + D1[2*t].y * v10[t].y +
                                D1[2*t].z * v10[t].z + D1[2*t].w * v10[t].w +
                                D1[2*t+1].x * v11[t].x + D1[2*t+1].y * v11[t].y +
                                D1[2*t+1].z * v11[t].z + D1[2*t+1].w * v11[t].w;
                    lp0 += __shfl_xor(lp0, 16, 64);   // sum over quads (o coverage)
                    lp0 += __shfl_xor(lp0, 32, 64);
                    lp1 += __shfl_xor(lp1, 16, 64);
                    lp1 += __shfl_xor(lp1, 32, 64);
                    e0[t] = __expf(lp0); se0 += e0[t]; // no max-subtract (|l| small)
                    e1[t] = __expf(lp1); se1 += e1[t];
                }
                if (lane < 32) sums[rr & 1][q][bl][w] = (q == 0) ? se0 : se1;
                // lgkmcnt-only drain: LDS write visible, W loads stay in flight.
                asm volatile("s_waitcnt lgkmcnt(0)" ::: "memory");
                __builtin_amdgcn_s_barrier();
                asm volatile("" ::: "memory");
                const floatx4 sa0 = *(const floatx4*)(&sums[rr & 1][0][bl][0]);
                const floatx4 sa1 = *(const floatx4*)(&sums[rr & 1][0][bl][4]);
                const floatx4 sb0 = *(const floatx4*)(&sums[rr & 1][1][bl][0]);
                const floatx4 sb1 = *(const floatx4*)(&sums[rr & 1][1][bl][4]);
                const float tot0 = sa0.x + sa0.y + sa0.z + sa0.w +
                                   sa1.x + sa1.y + sa1.z + sa1.w;
                const float tot1 = sb0.x + sb0.y + sb0.z + sb0.w +
                                   sb1.x + sb1.y + sb1.z + sb1.w;
                const float winv0 = __builtin_amdgcn_rcpf(tot0);
                const float winv1 = __builtin_amdgcn_rcpf(tot1);
#pragma unroll
                for (int t = 0; t < 4; ++t) {
                    const float wt0 = e0[t] * winv0;
                    const float wt1 = e1[t] * winv1;
                    accS0[2*t]   += wt0 * D0[2*t];
                    accS0[2*t+1] += wt0 * D0[2*t+1];
                    accS1[2*t]   += wt1 * D1[2*t];
                    accS1[2*t+1] += wt1 * D1[2*t+1];
                }
            }
#pragma unroll
            for (int m = 0; m < 8; ++m) pa[m] = pan[m];
        }
    }

    // store fp16 partials: co = w*128 + m*16 + 4q + reg (4 halves = 8B/store)
    const size_t sb = (((size_t)rc * 64 + b0 + bl)) * 1024 + w * 128 + 4 * q;
#pragma unroll
    for (int m = 0; m < 8; ++m) {
        const floatx4 a0v = accS0[m], a1v = accS1[m];
        const half4v h0 = {(_Float16)a0v.x, (_Float16)a0v.y, (_Float16)a0v.z, (_Float16)a0v.w};
        const half4v h1 = {(_Float16)a1v.x, (_Float16)a1v.y, (_Float16)a1v.z, (_Float16)a1v.w};
        *(half4v*)(s_part + sb + m * 16) = h0;
        *(half4v*)(s_part + sb + (size_t)16 * 1024 + m * 16) = h1;
    }
}

// Fused reduce(128 rc-partials fp16, fp32 accumulate) + squash.
// Grid: 64 b x 8 co-octs = 512 blocks; 256 thr = 8 k-groups x 32 half4.
__global__ __launch_bounds__(256)
void reduce_squash(const _Float16* __restrict__ sp, float scale,
                   float* __restrict__ vout, const float* __restrict__ vprev,
                   float* __restrict__ vsum) {
    const int b = blockIdx.x >> 3, oct = blockIdx.x & 7;
    const int t = threadIdx.x;
    const int kg = t >> 5, ci = t & 31;
    const size_t base = (size_t)b * 1024 + (size_t)oct * 128 + (size_t)ci * 4;

    floatx4 acc0 = (floatx4){0.f, 0.f, 0.f, 0.f};
    floatx4 acc1 = (floatx4){0.f, 0.f, 0.f, 0.f};
#pragma unroll
    for (int k = kg * 16; k < kg * 16 + 16; k += 2) {
        const half4v h0 = *(const half4v*)(sp + (size_t)k * 65536 + base);
        const half4v h1 = *(const half4v*)(sp + (size_t)(k + 1) * 65536 + base);
        acc0 += (floatx4){(float)h0.x, (float)h0.y, (float)h0.z, (float)h0.w};
        acc1 += (floatx4){(float)h1.x, (float)h1.y, (float)h1.z, (float)h1.w};
    }
    const floatx4 acc = acc0 + acc1;

    __shared__ __attribute__((aligned(16))) float red[8][128];
    *(floatx4*)(&red[kg][ci * 4]) = acc;
    __syncthreads();

    if (t < 128) {                     // element f = t : c = oct*4 + (t>>5), o = t&31
        float s = 0.f;
#pragma unroll
        for (int g = 0; g < 8; ++g) s += red[g][t];
        s *= scale;
        float n2 = s * s;              // norm over o: lane bits 0..4
        n2 += __shfl_xor(n2, 1, 64);
        n2 += __shfl_xor(n2, 2, 64);
        n2 += __shfl_xor(n2, 4, 64);
        n2 += __shfl_xor(n2, 8, 64);
        n2 += __shfl_xor(n2, 16, 64);
        const float norm = sqrtf(n2);
        const float f = (n2 / (1.f + n2)) / (norm + 1e-8f);
        const float vv = s * f;
        const size_t o = (size_t)b * 1024 + (size_t)oct * 128 + t;
        if (vout) vout[o] = vv;
        if (vsum) vsum[o] = vv + vprev[o];
    }
}

extern "C" void kernel_launch(void* const* d_in, const int* in_sizes, int n_in,
                              void* d_out, int out_size, void* d_ws, size_t ws_size,
                              hipStream_t stream) {
    const float* x = (const float*)d_in[0];   // [64,2048,16]
    const float* W = (const float*)d_in[1];   // [2048,32,32,16]
    float* out = (float*)d_out;               // [64,32,32]

    char* ws = (char*)d_ws;                   // ws >= 512 MB (harness fills 512MB)
    _Float16* Wh     = (_Float16*)ws;                               // 64 MB (paired)
    _Float16* s_part = (_Float16*)(ws + (size_t)67108864);          // 16 MB
    float* v1        = (float*)(ws + (size_t)67108864 + 33554432);             // 256 KB
    float* v12       = (float*)(ws + (size_t)67108864 + 33554432 + 262144);    // 256 KB

    const int ublocks = NG * NRC2;   // 256 = 1 block/CU

    // iter 1: reads W fp32, persists paired Wh fp16; 1/32 as squash pre-scale
    upass<0><<<ublocks, 512, 0, stream>>>(x, W, Wh, nullptr, s_part);
    reduce_squash<<<512, 256, 0, stream>>>(s_part, 1.f / 32.f, v1, nullptr, nullptr);

    // iter 2: logits = u.v1 ; keep only v12 = v1 + v2
    upass<1><<<ublocks, 512, 0, stream>>>(x, nullptr, Wh, v1, s_part);
    reduce_squash<<<512, 256, 0, stream>>>(s_part, 1.f, nullptr, v1, v12);

    // iter 3: logits = u.(v1+v2) ; output v3
    upass<2><<<ublocks, 512, 0, stream>>>(x, nullptr, Wh, v12, s_part);
    reduce_squash<<<512, 256, 0, stream>>>(s_part, 1.f, out, nullptr, nullptr);
}

// Round 24
// 284.565 us; speedup vs baseline: 1.8477x; 1.8477x over previous
//
#include <hip/hip_runtime.h>

// Capsule routing, B=64 R=2048 C=32 O=32 I=16, 3 routing iters.
// u_hat never materialized; recomputed per pass. Logit telescoping:
// b1 = u.v1 ; b2 = u.(v1+v2).
//
// R35: m-PAIRED Wh (16B loads, register-neutral). R32 post-mortem: the
//   r-paired attempt spilled (pa+pan half8 = +48 VGPRs over R30 => 307MB
//   scratch writes/upass, 525us). Load-width theory NOT tested. Retry
//   with zero register delta: pack fragments of m and m+1 (same r)
//   contiguous per lane -> a[4] half8 = 4 x b128 per rr (was 8 x b64),
//   a[4]+an[4] = 32 VGPRs = R30's a[8]+temps exactly. Same prefetch-
//   after-MFMA schedule, same softmax, same fp16 s_part. Lane addr
//   r*16384 + (w*64+bl)*32 + q*8 + p*512: wave = contiguous 1KB per p.
//   Pre-commit: neutral => load-width theory closed, declare floor.
// R30 (kept): fp16 s_part (16 MB); RCH=16, 256 blocks, bound=1.
// R25 (kept): wconv folded into upass<0> (fp32 W read, bg==0 persists Wh).
// R15 (kept): NG=2 b-fusion, 32 b/block; fused reduce_squash.
// R11 baseline: MFMA 16x16x16 per tile; D row=4q+reg, col=lane&15.

#define Bn 64
#define Rn 2048
#define Cn 32
#define On 32
#define In 16
#define RCH 16            // r per block
#define NRC2 (Rn / RCH)   // 128 r-chunks
#define NG 2              // fused b-groups of 32

typedef _Float16 half4v __attribute__((ext_vector_type(4)));
typedef _Float16 half8v __attribute__((ext_vector_type(8)));
typedef float floatx4 __attribute__((ext_vector_type(4)));

// s_part: [NRC2][64 b][1024 co] fp16 (16 MB)
// Wh m-paired layout, per r (16384 halfs):
//   half index = r*16384 + ((w*4 + (m>>1))*16 + bl)*32 + q*8 + (m&1)*4
template <int PHASE>
__global__ __launch_bounds__(512, 1)
void upass(const float* __restrict__ x, const float* __restrict__ Wfp,
           _Float16* __restrict__ Wh, const float* __restrict__ vroute,
           _Float16* __restrict__ s_part) {
    const int tid  = threadIdx.x;
    const int w    = tid >> 6;      // wave 0..7 -> c = 4w..4w+3
    const int lane = tid & 63;
    const int q    = lane >> 4;     // quad
    const int bl   = lane & 15;     // A row / B col / D col

    // XCD swizzle: the 2 bg-blocks of one rc are L and L+8 -> same XCD.
    const int L  = blockIdx.x;                  // [0,256)
    const int bg = (L >> 3) & 1;
    const int rc = (L & 7) | ((L >> 4) << 3);   // [0,128)
    const int b0 = bg * 32;

    // xs[rr][bb 32][20] halfs (pad 16->20: 8B-aligned b64, conflict-free)
    __shared__ __attribute__((aligned(16))) _Float16 xs[RCH * 32 * 20];
    __shared__ __attribute__((aligned(16))) float sums[2][2][16][8];

    // ---- v slice -> registers (r-invariant). g=0: b0+bl, g=1: b0+16+bl ----
    floatx4 v00[4], v01[4], v10[4], v11[4];
    if constexpr (PHASE > 0) {
        const float* vb0 = vroute + (size_t)(b0 + bl) * 1024 + 4 * q;
        const float* vb1 = vroute + (size_t)(b0 + 16 + bl) * 1024 + 4 * q;
#pragma unroll
        for (int t = 0; t < 4; ++t) {
            const int co = (w * 4 + t) * 32;
            v00[t] = *(const floatx4*)(vb0 + co);
            v01[t] = *(const floatx4*)(vb0 + co + 16);
            v10[t] = *(const floatx4*)(vb1 + co);
            v11[t] = *(const floatx4*)(vb1 + co + 16);
        }
    }

    // ---- preload x chunk -> fp16 LDS: 16 r x 32 b x 16 i ----
#pragma unroll
    for (int k = 0; k < 4; ++k) {
        const int u  = tid + k * 512;           // [0,2048)
        const int rr = u >> 7, bb = (u >> 2) & 31, iq = u & 3;
        const float4 xv = *(const float4*)(x + (size_t)(b0 + bb) * (Rn * In) +
                                           (size_t)(rc * RCH + rr) * In + iq * 4);
        union { _Float16 h[4]; uint2 u2; } p;
        p.h[0] = (_Float16)xv.x; p.h[1] = (_Float16)xv.y;
        p.h[2] = (_Float16)xv.z; p.h[3] = (_Float16)xv.w;
        *(uint2*)(xs + (rr * 32 + bb) * 20 + iq * 4) = p.u2;
    }
    __syncthreads();

    floatx4 accS0[8], accS1[8];
#pragma unroll
    for (int m = 0; m < 8; ++m) {
        accS0[m] = (floatx4){0.f, 0.f, 0.f, 0.f};
        accS1[m] = (floatx4){0.f, 0.f, 0.f, 0.f};
    }

    // per-lane base inside one r's 16384-half tile (m-pair p adds p*512)
    const size_t lb = (size_t)(w * 64 + bl) * 32 + q * 8;

    if constexpr (PHASE == 0) {
        // fp32 source base: W[r][co][i] linear; per-r stride 16384 elems
        const size_t abase = ((size_t)(rc * RCH) * 1024 + w * 128 + bl) * 16 + 4 * q;
        for (int rr = 0; rr < RCH; ++rr) {
            const float* Wf = Wfp + abase + (size_t)rr * 16384;
            half4v af[8];
#pragma unroll
            for (int m = 0; m < 8; ++m) {
                const float4 t4 = *(const float4*)(Wf + m * 256);
                af[m] = (half4v){(_Float16)t4.x, (_Float16)t4.y,
                                 (_Float16)t4.z, (_Float16)t4.w};
            }
            if (bg == 0) {
                _Float16* whp = Wh + (size_t)(rc * RCH + rr) * 16384 + lb;
#pragma unroll
                for (int m = 0; m < 8; ++m)
                    *(half4v*)(whp + (m >> 1) * 512 + (m & 1) * 4) = af[m];
            }
            const half4v b0v = *(const half4v*)(xs + (rr * 32 + bl) * 20 + 4 * q);
            const half4v b1v = *(const half4v*)(xs + (rr * 32 + 16 + bl) * 20 + 4 * q);
#pragma unroll
            for (int m = 0; m < 8; ++m) {
                accS0[m] = __builtin_amdgcn_mfma_f32_16x16x16f16(af[m], b0v, accS0[m], 0, 0, 0);
                accS1[m] = __builtin_amdgcn_mfma_f32_16x16x16f16(af[m], b1v, accS1[m], 0, 0, 0);
            }
        }
    } else {
        const size_t wb = (size_t)(rc * RCH) * 16384 + lb;
        // prime fragments for rr=0: 4 x b128
        half8v a[4];
#pragma unroll
        for (int p = 0; p < 4; ++p) a[p] = *(const half8v*)(Wh + wb + p * 512);
        half4v bf0 = *(const half4v*)(xs + bl * 20 + 4 * q);
        half4v bf1 = *(const half4v*)(xs + (16 + bl) * 20 + 4 * q);

        for (int rr = 0; rr < RCH; ++rr) {
            const int rn = (rr + 1 < RCH) ? rr + 1 : rr;     // clamped prefetch idx
            const _Float16* Wn = Wh + wb + (size_t)rn * 16384;

            floatx4 D0[8], D1[8];
#pragma unroll
            for (int p = 0; p < 4; ++p) {
                const half4v alo = __builtin_shufflevector(a[p], a[p], 0, 1, 2, 3);
                const half4v ahi = __builtin_shufflevector(a[p], a[p], 4, 5, 6, 7);
                D0[2*p]   = __builtin_amdgcn_mfma_f32_16x16x16f16(
                                alo, bf0, (floatx4){0.f, 0.f, 0.f, 0.f}, 0, 0, 0);
                D0[2*p+1] = __builtin_amdgcn_mfma_f32_16x16x16f16(
                                ahi, bf0, (floatx4){0.f, 0.f, 0.f, 0.f}, 0, 0, 0);
                D1[2*p]   = __builtin_amdgcn_mfma_f32_16x16x16f16(
                                alo, bf1, (floatx4){0.f, 0.f, 0.f, 0.f}, 0, 0, 0);
                D1[2*p+1] = __builtin_amdgcn_mfma_f32_16x16x16f16(
                                ahi, bf1, (floatx4){0.f, 0.f, 0.f, 0.f}, 0, 0, 0);
            }

            // issue rr+1 fragment loads NOW; in flight across the barrier.
            const half4v bn0 = *(const half4v*)(xs + (rn * 32 + bl) * 20 + 4 * q);
            const half4v bn1 = *(const half4v*)(xs + (rn * 32 + 16 + bl) * 20 + 4 * q);
            half8v an[4];
#pragma unroll
            for (int p = 0; p < 4; ++p) an[p] = *(const half8v*)(Wn + p * 512);

            // logits l[b,c] = sum_o u*v ; tile 2t: o=4q+reg, 2t+1: o=16+4q+reg
            float e0[4], e1[4], se0 = 0.f, se1 = 0.f;
#pragma unroll
            for (int t = 0; t < 4; ++t) {
                float lp0 = D0[2*t].x * v00[t].x + D0[2*t].y * v00[t].y +
                            D0[2*t].z * v00[t].z + D0[2*t].w * v00[t].w +
                            D0[2*t+1].x * v01[t].x + D0[2*t+1].y * v01[t].y +
                            D0[2*t+1].z * v01[t].z + D0[2*t+1].w * v01[t].w;
                float lp1 = D1[2*t].x * v10[t].x + D1[2*t].y * v10[t].y +
                            D1[2*t].z * v10[t].z + D1[2*t].w * v10[t].w +
                            D1[2*t+1].x * v11[t].x + D1[2*t+1].y * v11[t].y +
                            D1[2*t+1].z * v11[t].z + D1[2*t+1].w * v11[t].w;
                lp0 += __shfl_xor(lp0, 16, 64);   // sum over quads (o coverage)
                lp0 += __shfl_xor(lp0, 32, 64);
                lp1 += __shfl_xor(lp1, 16, 64);
                lp1 += __shfl_xor(lp1, 32, 64);
                e0[t] = __expf(lp0); se0 += e0[t]; // no max-subtract (|l| small)
                e1[t] = __expf(lp1); se1 += e1[t];
            }
            if (lane < 32) sums[rr & 1][q][bl][w] = (q == 0) ? se0 : se1;
            // lgkmcnt-only drain: LDS write visible, W loads stay in flight.
            asm volatile("s_waitcnt lgkmcnt(0)" ::: "memory");
            __builtin_amdgcn_s_barrier();
            asm volatile("" ::: "memory");
            const floatx4 sa0 = *(const floatx4*)(&sums[rr & 1][0][bl][0]);
            const floatx4 sa1 = *(const floatx4*)(&sums[rr & 1][0][bl][4]);
            const floatx4 sb0 = *(const floatx4*)(&sums[rr & 1][1][bl][0]);
            const floatx4 sb1 = *(const floatx4*)(&sums[rr & 1][1][bl][4]);
            const float tot0 = sa0.x + sa0.y + sa0.z + sa0.w +
                               sa1.x + sa1.y + sa1.z + sa1.w;
            const float tot1 = sb0.x + sb0.y + sb0.z + sb0.w +
                               sb1.x + sb1.y + sb1.z + sb1.w;
            const float winv0 = __builtin_amdgcn_rcpf(tot0);
            const float winv1 = __builtin_amdgcn_rcpf(tot1);
#pragma unroll
            for (int t = 0; t < 4; ++t) {
                const float wt0 = e0[t] * winv0;
                const float wt1 = e1[t] * winv1;
                accS0[2*t]   += wt0 * D0[2*t];
                accS0[2*t+1] += wt0 * D0[2*t+1];
                accS1[2*t]   += wt1 * D1[2*t];
                accS1[2*t+1] += wt1 * D1[2*t+1];
            }
#pragma unroll
            for (int p = 0; p < 4; ++p) a[p] = an[p];
            bf0 = bn0; bf1 = bn1;
        }
    }

    // store fp16 partials: co = w*128 + m*16 + 4q + reg (4 halves = 8B/store)
    const size_t sb = (((size_t)rc * 64 + b0 + bl)) * 1024 + w * 128 + 4 * q;
#pragma unroll
    for (int m = 0; m < 8; ++m) {
        const floatx4 a0v = accS0[m], a1v = accS1[m];
        const half4v h0 = {(_Float16)a0v.x, (_Float16)a0v.y, (_Float16)a0v.z, (_Float16)a0v.w};
        const half4v h1 = {(_Float16)a1v.x, (_Float16)a1v.y, (_Float16)a1v.z, (_Float16)a1v.w};
        *(half4v*)(s_part + sb + m * 16) = h0;
        *(half4v*)(s_part + sb + (size_t)16 * 1024 + m * 16) = h1;
    }
}

// Fused reduce(128 rc-partials fp16, fp32 accumulate) + squash.
// Grid: 64 b x 8 co-octs = 512 blocks; 256 thr = 8 k-groups x 32 half4.
__global__ __launch_bounds__(256)
void reduce_squash(const _Float16* __restrict__ sp, float scale,
                   float* __restrict__ vout, const float* __restrict__ vprev,
                   float* __restrict__ vsum) {
    const int b = blockIdx.x >> 3, oct = blockIdx.x & 7;
    const int t = threadIdx.x;
    const int kg = t >> 5, ci = t & 31;
    const size_t base = (size_t)b * 1024 + (size_t)oct * 128 + (size_t)ci * 4;

    floatx4 acc0 = (floatx4){0.f, 0.f, 0.f, 0.f};
    floatx4 acc1 = (floatx4){0.f, 0.f, 0.f, 0.f};
#pragma unroll
    for (int k = kg * 16; k < kg * 16 + 16; k += 2) {
        const half4v h0 = *(const half4v*)(sp + (size_t)k * 65536 + base);
        const half4v h1 = *(const half4v*)(sp + (size_t)(k + 1) * 65536 + base);
        acc0 += (floatx4){(float)h0.x, (float)h0.y, (float)h0.z, (float)h0.w};
        acc1 += (floatx4){(float)h1.x, (float)h1.y, (float)h1.z, (float)h1.w};
    }
    const floatx4 acc = acc0 + acc1;

    __shared__ __attribute__((aligned(16))) float red[8][128];
    *(floatx4*)(&red[kg][ci * 4]) = acc;
    __syncthreads();

    if (t < 128) {                     // element f = t : c = oct*4 + (t>>5), o = t&31
        float s = 0.f;
#pragma unroll
        for (int g = 0; g < 8; ++g) s += red[g][t];
        s *= scale;
        float n2 = s * s;              // norm over o: lane bits 0..4
        n2 += __shfl_xor(n2, 1, 64);
        n2 += __shfl_xor(n2, 2, 64);
        n2 += __shfl_xor(n2, 4, 64);
        n2 += __shfl_xor(n2, 8, 64);
        n2 += __shfl_xor(n2, 16, 64);
        const float norm = sqrtf(n2);
        const float f = (n2 / (1.f + n2)) / (norm + 1e-8f);
        const float vv = s * f;
        const size_t o = (size_t)b * 1024 + (size_t)oct * 128 + t;
        if (vout) vout[o] = vv;
        if (vsum) vsum[o] = vv + vprev[o];
    }
}

extern "C" void kernel_launch(void* const* d_in, const int* in_sizes, int n_in,
                              void* d_out, int out_size, void* d_ws, size_t ws_size,
                              hipStream_t stream) {
    const float* x = (const float*)d_in[0];   // [64,2048,16]
    const float* W = (const float*)d_in[1];   // [2048,32,32,16]
    float* out = (float*)d_out;               // [64,32,32]

    char* ws = (char*)d_ws;                   // ws >= 512 MB (harness fills 512MB)
    _Float16* Wh     = (_Float16*)ws;                               // 64 MB (m-paired)
    _Float16* s_part = (_Float16*)(ws + (size_t)67108864);          // 16 MB
    float* v1        = (float*)(ws + (size_t)67108864 + 33554432);             // 256 KB
    float* v12       = (float*)(ws + (size_t)67108864 + 33554432 + 262144);    // 256 KB

    const int ublocks = NG * NRC2;   // 256 = 1 block/CU

    // iter 1: reads W fp32, persists m-paired Wh fp16; 1/32 as squash pre-scale
    upass<0><<<ublocks, 512, 0, stream>>>(x, W, Wh, nullptr, s_part);
    reduce_squash<<<512, 256, 0, stream>>>(s_part, 1.f / 32.f, v1, nullptr, nullptr);

    // iter 2: logits = u.v1 ; keep only v12 = v1 + v2
    upass<1><<<ublocks, 512, 0, stream>>>(x, nullptr, Wh, v1, s_part);
    reduce_squash<<<512, 256, 0, stream>>>(s_part, 1.f, nullptr, v1, v12);

    // iter 3: logits = u.(v1+v2) ; output v3
    upass<2><<<ublocks, 512, 0, stream>>>(x, nullptr, Wh, v12, s_part);
    reduce_squash<<<512, 256, 0, stream>>>(s_part, 1.f, out, nullptr, nullptr);
}